// Round 4
// baseline (753.098 us; speedup 1.0000x reference)
//
#include <hip/hip_runtime.h>

#define GLOBAL_AS __attribute__((address_space(1)))
#define LDS_AS    __attribute__((address_space(3)))

typedef __bf16 bf16x8 __attribute__((ext_vector_type(8)));
typedef float  f32x16 __attribute__((ext_vector_type(16)));

// Problem dims (fixed by the reference)
constexpr int SRC_STRIDE = 8192 * 80;         // floats per batch row: 655360
constexpr int TOUT       = 2728;              // output time steps
constexpr long OUT_ELEMS = (long)TOUT * 16 * 1024;  // 44695552
constexpr int SRC_ELEMS  = 32 * SRC_STRIDE;   // 20971520
constexpr int W_ELEMS    = 1024 * 640;        // 655360
constexpr int MBLK       = 682;               // 87296 / 128 (exact)

__device__ __forceinline__ unsigned short f2bf(float f) {
    union { float f; unsigned u; } a; a.f = f;
    unsigned r = a.u + 0x7FFF + ((a.u >> 16) & 1);   // round-to-nearest-even
    return (unsigned short)(r >> 16);
}

// fp32 -> bf16 linear copy (A / src), 4 elements/thread
__global__ void cvt_kernel(const float* __restrict__ in, unsigned short* __restrict__ out, int n4) {
    int i = blockIdx.x * blockDim.x + threadIdx.x;
    if (i >= n4) return;
    float4 v = ((const float4*)in)[i];
    ushort4 o;
    o.x = f2bf(v.x); o.y = f2bf(v.y); o.z = f2bf(v.z); o.w = f2bf(v.w);
    ((ushort4*)out)[i] = o;
}

// W -> bf16, pre-swizzled into MFMA B-fragment order (verified in R3):
// Wfrag[((bn*80 + cc)*64 + nl)*8 + e] = bf16( W[(bn*64+nl)*640 + cc*8 + e] )
// => B-frag for (c,nt): lane(b,q) reads elems  nc*40960 + c*1024 + q*512 + nt*256 + b*8
//    holding W[n = nc*64+nt*32+b][k = c*16 + q*8 + e]
__global__ void cvt_w_frag(const float* __restrict__ W, unsigned short* __restrict__ out) {
    int i = blockIdx.x * blockDim.x + threadIdx.x;    // 0 .. 81919
    int nl = i & 63;
    int c  = (i >> 6) % 80;
    int bn = i / 5120;
    const float* src = W + (bn * 64 + nl) * 640 + c * 8;
    float4 v0 = ((const float4*)src)[0];
    float4 v1 = ((const float4*)src)[1];
    ushort4 o0, o1;
    o0.x = f2bf(v0.x); o0.y = f2bf(v0.y); o0.z = f2bf(v0.z); o0.w = f2bf(v0.w);
    o1.x = f2bf(v1.x); o1.y = f2bf(v1.y); o1.z = f2bf(v1.z); o1.w = f2bf(v1.w);
    ((ushort4*)(out + (long)i * 8))[0] = o0;
    ((ushort4*)(out + (long)i * 8))[1] = o1;
}

// out_lengths = src_lengths // 3 - 2, written as fp32 after the main output
__global__ void lengths_kernel(const int* __restrict__ len, float* __restrict__ out) {
    int i = threadIdx.x;
    if (i < 32) out[OUT_ELEMS + i] = (float)(len[i] / 3 - 2);
}

// Fused GEMM (M=87296, N=1024, K=640) + bias + GLU.
// Block: 128 M (4 t-groups x 32 b) x full N=1024. 512 threads / 8 waves.
// A-slice staged ONCE in LDS (32 b-rows x 1536-elem windows, +8 pad) -> 1 barrier.
// B streams from L2 in fragment order (Wfrag, 1.3 MB, L2-resident).
// Wave tile: 128M x 64N (nc = w*2+pass), mfma_f32_32x32x16_bf16.
// C/D: col=lane&31, row=(r&3)+8*(r>>2)+4*q; GLU pairs value reg r with gate r+8.
__global__ __launch_bounds__(512, 2) void glu_gemm(
        const __bf16* __restrict__ Ac,      // bf16 copy of src, same layout
        const __bf16* __restrict__ Wfrag,
        const float* __restrict__ bias,
        float* __restrict__ out) {
    __shared__ __bf16 lA[32 * 1544];   // 98816 B; row b at b*1544, window of 1536

    const int tid  = threadIdx.x;
    const int lane = tid & 63;
    const int w    = tid >> 6;        // wave 0..7
    const int b    = lane & 31;       // MFMA row within 32 (batch index)
    const int q    = lane >> 5;       // k-half within fragment

    const int bm = blockIdx.x;        // 0..681, block t-range [bm*4, bm*4+3]

    // ---- stage A: per b-row, window src elems [bm*960, bm*960+1536) ----
    // 32 rows x 3 thirds = 96 wave-issues; wave w does b = w*4..w*4+3.
    // LDS dest is wave-uniform base + lane*16B (constraint of global_load_lds).
#pragma unroll
    for (int j = 0; j < 12; ++j) {
        const int bb = w * 4 + (j & 3);
        const int th = j >> 2;
        __builtin_amdgcn_global_load_lds(
            (const GLOBAL_AS void*)(Ac + (long)bb * SRC_STRIDE + bm * 960 + th * 512 + lane * 8),
            (LDS_AS void*)(lA + bb * 1544 + th * 512 + lane * 8), 16, 0, 0);
    }

    __syncthreads();                   // the ONLY barrier

    // A frag base: lane(b,q) row base; frag (tl,c) at uniform imm tl*240 + c*16
    const __bf16* lab = lA + b * 1544 + q * 8;
    const int bo = q * 512 + b * 8;

    for (int pass = 0; pass < 2; ++pass) {
        const int nc = w * 2 + pass;
        const __bf16* wsrc = Wfrag + nc * 40960 + bo;

        f32x16 acc[4][2] = {};

        bf16x8 aC[4], aN[4], bC[2], bN[2], bN2[2];
#pragma unroll
        for (int tl = 0; tl < 4; ++tl)
            aC[tl] = *(const bf16x8*)(lab + tl * 240);
        bC[0] = *(const bf16x8*)(wsrc);
        bC[1] = *(const bf16x8*)(wsrc + 256);
        bN[0] = *(const bf16x8*)(wsrc + 1024);
        bN[1] = *(const bf16x8*)(wsrc + 1024 + 256);

#pragma unroll
        for (int c = 0; c < 40; ++c) {
            if (c < 39) {
#pragma unroll
                for (int tl = 0; tl < 4; ++tl)
                    aN[tl] = *(const bf16x8*)(lab + tl * 240 + (c + 1) * 16);
            }
            if (c < 38) {
                bN2[0] = *(const bf16x8*)(wsrc + (c + 2) * 1024);
                bN2[1] = *(const bf16x8*)(wsrc + (c + 2) * 1024 + 256);
            }
#pragma unroll
            for (int tl = 0; tl < 4; ++tl) {
                acc[tl][0] = __builtin_amdgcn_mfma_f32_32x32x16_bf16(aC[tl], bC[0], acc[tl][0], 0, 0, 0);
                acc[tl][1] = __builtin_amdgcn_mfma_f32_32x32x16_bf16(aC[tl], bC[1], acc[tl][1], 0, 0, 0);
            }
            if (c < 39) {
#pragma unroll
                for (int tl = 0; tl < 4; ++tl) aC[tl] = aN[tl];
                bC[0] = bN[0]; bC[1] = bN[1];
                bN[0] = bN2[0]; bN[1] = bN2[1];
            }
        }

        // ---- epilogue: bias + GLU, in-register ----
        const float bv0 = bias[nc * 64 + b];
        const float bv1 = bias[nc * 64 + 32 + b];
#pragma unroll
        for (int tl = 0; tl < 4; ++tl) {
            const int t = bm * 4 + tl;
#pragma unroll
            for (int nt = 0; nt < 2; ++nt) {
                const float bvv = nt ? bv1 : bv0;
                const long ncol = nc * 64 + nt * 32 + b;
#pragma unroll
                for (int r = 0; r < 8; ++r) {
                    const int brow = (r & 3) + 8 * (r >> 2) + 4 * q;  // value row 0..15
                    float v = acc[tl][nt][r] + bvv;
                    float g = acc[tl][nt][r + 8] + bvv;               // gate row +16
                    float s = 1.0f / (1.0f + __expf(-g));
                    out[((long)(t * 16 + brow)) * 1024 + ncol] = v * s;
                }
            }
        }
    }
}

extern "C" void kernel_launch(void* const* d_in, const int* in_sizes, int n_in,
                              void* d_out, int out_size, void* d_ws, size_t ws_size,
                              hipStream_t stream) {
    const float* src  = (const float*)d_in[0];
    const int*   lens = (const int*)d_in[1];
    const float* Wf   = (const float*)d_in[2];
    const float* bias = (const float*)d_in[3];
    float* out = (float*)d_out;

    unsigned short* srcb  = (unsigned short*)d_ws;         // 20971520 bf16 = 41.9 MB
    unsigned short* wfrag = srcb + SRC_ELEMS;              // 655360 bf16 = 1.3 MB

    // bf16 pre-passes
    cvt_kernel<<<SRC_ELEMS / 4 / 256, 256, 0, stream>>>(src, srcb, SRC_ELEMS / 4);
    cvt_w_frag<<<W_ELEMS / 8 / 256, 256, 0, stream>>>(Wf, wfrag);

    // out_lengths
    lengths_kernel<<<1, 64, 0, stream>>>(lens, out);

    // fused GEMM + GLU: 682 M-blocks, each covers full N
    glu_gemm<<<MBLK, 512, 0, stream>>>((const __bf16*)srcb,
                                       (const __bf16*)wfrag, bias, out);
}